// Round 4
// baseline (87.785 us; speedup 1.0000x reference)
//
#include <hip/hip_runtime.h>
#include <math.h>

#define NFRAMES 16384
#define NJOINTS 22
#define NPATHS  5
#define NPAIRS  (NPATHS * NPATHS)
#define NSEG    16      // segments per motion: 3+3+4+3+3
#define GSTRIDE 32      // padded gli row stride (floats) -> 128B-aligned rows

// Per-segment float offsets (joint*3) into a frame: {start, end}.
// Segments: path0 (2,5)(5,8)(8,11); path1 (1,4)(4,7)(7,10);
// path2 (3,6)(6,9)(9,12)(12,15); path3 (14,17)(17,19)(19,21);
// path4 (13,16)(16,18)(18,20).
__constant__ int2 c_seg[NSEG] = {
    {6,15},{15,24},{24,33},
    {3,12},{12,21},{21,30},
    {9,18},{18,27},{27,36},{36,45},
    {42,51},{51,57},{57,63},
    {39,48},{48,54},{54,60}
};
__constant__ int c_pstart[NPATHS] = {0, 3, 6, 10, 13};
__constant__ int c_plen[NPATHS]   = {3, 3, 4, 3, 3};

struct F3 { float x, y, z; };
__device__ __forceinline__ F3 mk3(float x, float y, float z) { F3 r; r.x=x; r.y=y; r.z=z; return r; }
__device__ __forceinline__ F3 ld3(const float* p) { return mk3(p[0], p[1], p[2]); }
__device__ __forceinline__ F3 sub3(F3 a, F3 b) { return mk3(a.x-b.x, a.y-b.y, a.z-b.z); }
__device__ __forceinline__ float dot3(F3 a, F3 b) { return a.x*b.x + a.y*b.y + a.z*b.z; }
__device__ __forceinline__ F3 cross3(F3 a, F3 b) {
    return mk3(a.y*b.z - a.z*b.y,
               a.z*b.x - a.x*b.z,
               a.x*b.y - a.y*b.x);
}

// asin via A&S 4.4.45 (degree-3): acos(a)=sqrt(1-a)*poly(a), |eps|<=6.7e-5 rad.
__device__ __forceinline__ float fast_asin(float x) {
    float a = fabsf(x);
    float p = fmaf(a, -0.0187293f,  0.0742610f);
    p = fmaf(a, p, -0.2121144f);
    p = fmaf(a, p,  1.5707288f);
    float r = 1.5707963268f - __builtin_amdgcn_sqrtf(1.0f - a) * p;
    return copysignf(r, x);
}

// asin(clamp(d / sqrt(ma*mb))) with jnp safe-normalize semantics
// (zero-norm face -> normalized vec = 0 -> dot 0 -> asin 0)
__device__ __forceinline__ float asin_term(float d, float ma, float mb) {
    float rs = __builtin_amdgcn_rsqf(ma * mb);
    float x = fminf(1.0f, fmaxf(-1.0f, d * rs));
    float r = fast_asin(x);
    return (ma > 0.0f && mb > 0.0f) ? r : 0.0f;
}

__device__ __forceinline__ float bfly_min(float v) {
#pragma unroll
    for (int k = 1; k < 32; k <<= 1) v = fminf(v, __shfl_xor(v, k, 32));
    return v;
}
__device__ __forceinline__ float bfly_max(float v) {
#pragma unroll
    for (int k = 1; k < 32; k <<= 1) v = fmaxf(v, __shfl_xor(v, k, 32));
    return v;
}

// One block (256 threads) per frame. Thread t computes the GLI term for
// segment pair (i = t>>4 of motion1, j = t&15 of motion2) with points read
// directly from global (L1 broadcast). Wave 1 (lanes 64..127) additionally
// computes the bbox-overlap flag via width-32 shuffle reductions. After one
// barrier, 25 threads bin-reduce via a fully unrolled padded LDS gather.
__global__ __launch_bounds__(256) void k_gli(const float* __restrict__ m1,
                                             const float* __restrict__ m2,
                                             float* __restrict__ gli,
                                             int* __restrict__ ov) {
    __shared__ float sT[257];   // sT[256] = 0.0 pad slot

    int f = blockIdx.x;
    int t = threadIdx.x;
    const float* a = m1 + (size_t)f * (NJOINTS * 3);
    const float* b = m2 + (size_t)f * (NJOINTS * 3);

    int i = t >> 4;
    int j = t & 15;
    int2 o1 = c_seg[i];
    int2 o2 = c_seg[j];
    F3 s1 = ld3(a + o1.x);
    F3 e1 = ld3(a + o1.y);
    F3 s2 = ld3(b + o2.x);
    F3 e2 = ld3(b + o2.y);

    F3 r12 = sub3(e1, s1);
    F3 r13 = sub3(s2, s1);
    F3 r14 = sub3(e2, s1);

    // Faces via 3 crosses:
    //   f0 = r13 x r14, c1 = r12 x r13, c2 = r12 x r14
    //   f1 = c2, f2 = c2 - c1 - f0, f3 = -c1
    //   sign = dot(cross(r34, r12), r13) = -dot(c2, r13)
    F3 f0 = cross3(r13, r14);
    F3 c1 = cross3(r12, r13);
    F3 c2 = cross3(r12, r14);
    F3 f2 = sub3(sub3(c2, c1), f0);

    float q0 = dot3(f0, f0);
    float q1 = dot3(c2, c2);
    float q2 = dot3(f2, f2);
    float q3 = dot3(c1, c1);

    float g = asin_term( dot3(f0, c2), q0, q1)
            + asin_term( dot3(c2, f2), q1, q2)
            + asin_term(-dot3(f2, c1), q2, q3)
            + asin_term(-dot3(c1, f0), q3, q0);

    float sg = -dot3(c2, r13);
    sT[t] = (sg > 0.0f) ? g : -g;
    if (t == 0) sT[256] = 0.0f;

    // bbox overlap on wave 1; lanes 64..95 form one width-32 shuffle group.
    if (t >= 64 && t < 128) {
        int jj = t - 64;
        if (jj > NJOINTS - 1) jj = NJOINTS - 1;   // pad lanes replicate joint 21
        float ax = a[jj * 3 + 0], az = a[jj * 3 + 2];
        float bx = b[jj * 3 + 0], bz = b[jj * 3 + 2];
        float x1n = bfly_min(ax), x1x = bfly_max(ax);
        float z1n = bfly_min(az), z1x = bfly_max(az);
        float x2n = bfly_min(bx), x2x = bfly_max(bx);
        float z2n = bfly_min(bz), z2x = bfly_max(bz);
        if (t == 64) {
            bool ovx = !((x1x < x2n) || (x2x < x1n));
            bool ovz = !((z1x < z2n) || (z2x < z1n));
            ov[f] = (ovx && ovz) ? 1 : 0;
        }
    }
    __syncthreads();

    if (t < NPAIRS) {
        int pa = (t * 205) >> 10;   // t/5 for t<25
        int pb = t - pa * 5;        // t%5
        int ia0 = c_pstart[pa], na = c_plen[pa];
        int ib0 = c_pstart[pb], nb = c_plen[pb];
        float s = 0.0f;
#pragma unroll
        for (int ka = 0; ka < 4; ka++) {
#pragma unroll
            for (int kb = 0; kb < 4; kb++) {
                int idx = (ka < na && kb < nb) ? ((ia0 + ka) * 16 + (ib0 + kb)) : 256;
                s += sT[idx];
            }
        }
        gli[(size_t)f * GSTRIDE + t] = s * 0.07957747154594767f;  // 1/(4*pi)
    }
}

// out[f] = max_j | gli[f+1][j]*mask[f+1] - gli[f][j]*mask[f] |
// mask[i] = ov[i-1] | ov[i] | ov[i+1]  (out-of-range -> false)
__global__ void k_out(const float* __restrict__ gli, const int* __restrict__ ov,
                      float* __restrict__ out) {
    int f = blockIdx.x * blockDim.x + threadIdx.x;
    if (f >= NFRAMES - 1) return;

    int m0 = ov[f];
    if (f > 0) m0 |= ov[f - 1];
    m0 |= ov[f + 1];

    int m1 = ov[f + 1] | ov[f];
    if (f + 2 <= NFRAMES - 1) m1 |= ov[f + 2];

    float ma = m0 ? 1.0f : 0.0f;
    float mb = m1 ? 1.0f : 0.0f;

    const float4* g0v = (const float4*)(gli + (size_t)f * GSTRIDE);        // 128B-aligned
    const float4* g1v = (const float4*)(gli + (size_t)(f + 1) * GSTRIDE);
    float v = 0.0f;
#pragma unroll
    for (int q = 0; q < 6; q++) {
        float4 u0 = g0v[q];
        float4 u1 = g1v[q];
        v = fmaxf(v, fabsf(u1.x * mb - u0.x * ma));
        v = fmaxf(v, fabsf(u1.y * mb - u0.y * ma));
        v = fmaxf(v, fabsf(u1.z * mb - u0.z * ma));
        v = fmaxf(v, fabsf(u1.w * mb - u0.w * ma));
    }
    {
        float u0 = ((const float*)g0v)[24];
        float u1 = ((const float*)g1v)[24];
        v = fmaxf(v, fabsf(u1 * mb - u0 * ma));
    }
    out[f] = v;
}

extern "C" void kernel_launch(void* const* d_in, const int* in_sizes, int n_in,
                              void* d_out, int out_size, void* d_ws, size_t ws_size,
                              hipStream_t stream) {
    const float* m1 = (const float*)d_in[0];
    const float* m2 = (const float*)d_in[1];
    float* out = (float*)d_out;

    float* gli = (float*)d_ws;                          // NFRAMES*GSTRIDE floats = 2 MB
    int* ov = (int*)(gli + (size_t)NFRAMES * GSTRIDE);  // NFRAMES ints

    k_gli<<<NFRAMES, 256, 0, stream>>>(m1, m2, gli, ov);

    {
        int threads = 256;
        int blocks = (NFRAMES - 1 + threads - 1) / threads;
        k_out<<<blocks, threads, 0, stream>>>(gli, ov, out);
    }
}

// Round 5
// 84.639 us; speedup vs baseline: 1.0372x; 1.0372x over previous
//
#include <hip/hip_runtime.h>
#include <math.h>

#define NFRAMES 16384
#define NJOINTS 22
#define NPATHS  5
#define NPAIRS  (NPATHS * NPATHS)
#define NSEG    16      // segments per motion: 3+3+4+3+3
#define GSTRIDE 32      // padded gli row stride (floats) -> 128B-aligned rows

// Per-segment float offsets (joint*3) into a frame: {start, end}.
// path0 (2,5)(5,8)(8,11); path1 (1,4)(4,7)(7,10);
// path2 (3,6)(6,9)(9,12)(12,15); path3 (14,17)(17,19)(19,21);
// path4 (13,16)(16,18)(18,20).
__constant__ int2 c_seg[NSEG] = {
    {6,15},{15,24},{24,33},
    {3,12},{12,21},{21,30},
    {9,18},{18,27},{27,36},{36,45},
    {42,51},{51,57},{57,63},
    {39,48},{48,54},{54,60}
};
__constant__ int c_pstart[NPATHS] = {0, 3, 6, 10, 13};
__constant__ int c_plen[NPATHS]   = {3, 3, 4, 3, 3};

struct F3 { float x, y, z; };
__device__ __forceinline__ F3 mk3(float x, float y, float z) { F3 r; r.x=x; r.y=y; r.z=z; return r; }
__device__ __forceinline__ F3 sub3(F3 a, F3 b) { return mk3(a.x-b.x, a.y-b.y, a.z-b.z); }
__device__ __forceinline__ float dot3(F3 a, F3 b) { return a.x*b.x + a.y*b.y + a.z*b.z; }
__device__ __forceinline__ F3 cross3(F3 a, F3 b) {
    return mk3(a.y*b.z - a.z*b.y,
               a.z*b.x - a.x*b.z,
               a.x*b.y - a.y*b.x);
}

// asin via A&S 4.4.45 (degree-3): acos(a)=sqrt(1-a)*poly(a), |eps|<=6.7e-5 rad.
__device__ __forceinline__ float fast_asin(float x) {
    float a = fabsf(x);
    float p = fmaf(a, -0.0187293f,  0.0742610f);
    p = fmaf(a, p, -0.2121144f);
    p = fmaf(a, p,  1.5707288f);
    float r = 1.5707963268f - __builtin_amdgcn_sqrtf(1.0f - a) * p;
    return copysignf(r, x);
}

// asin(clamp(d / sqrt(ma*mb))) with jnp safe-normalize semantics
// (zero-norm face -> normalized vec = 0 -> dot 0 -> asin 0)
__device__ __forceinline__ float asin_term(float d, float ma, float mb) {
    float rs = __builtin_amdgcn_rsqf(ma * mb);
    float x = fminf(1.0f, fmaxf(-1.0f, d * rs));
    float r = fast_asin(x);
    return (ma > 0.0f && mb > 0.0f) ? r : 0.0f;
}

// One block (256 threads) per frame.
//  - waves 0/1 stage motion1's 66 floats, waves 2/3 stage motion2's (coalesced)
//  - thread t computes the GLI term for segment pair (t>>4, t&15) from LDS
//  - wave 1 additionally computes the bbox-overlap flag: lanes 64..95 reduce
//    motion1's x/z extents, lanes 96..127 motion2's (width-32 shuffles), lane
//    64 combines via width-64 shuffles and writes ov[f] (no extra barrier)
//  - after one barrier, 25 threads bin-reduce via an unrolled padded gather
__global__ __launch_bounds__(256) void k_gli(const float* __restrict__ m1,
                                             const float* __restrict__ m2,
                                             float* __restrict__ gli,
                                             int* __restrict__ ov) {
    __shared__ float sA[NJOINTS * 3];
    __shared__ float sB[NJOINTS * 3];
    __shared__ float sT[257];   // sT[256] = 0.0 pad slot

    int f = blockIdx.x;
    int t = threadIdx.x;
    const float* a = m1 + (size_t)f * (NJOINTS * 3);
    const float* b = m2 + (size_t)f * (NJOINTS * 3);
    if (t < NJOINTS * 3) sA[t] = a[t];
    else if (t >= 128 && t < 128 + NJOINTS * 3) sB[t - 128] = b[t - 128];
    __syncthreads();

    int i = t >> 4;
    int j = t & 15;
    int2 o1 = c_seg[i];
    int2 o2 = c_seg[j];
    F3 s1 = mk3(sA[o1.x], sA[o1.x+1], sA[o1.x+2]);
    F3 e1 = mk3(sA[o1.y], sA[o1.y+1], sA[o1.y+2]);
    F3 s2 = mk3(sB[o2.x], sB[o2.x+1], sB[o2.x+2]);
    F3 e2 = mk3(sB[o2.y], sB[o2.y+1], sB[o2.y+2]);

    F3 r12 = sub3(e1, s1);
    F3 r13 = sub3(s2, s1);
    F3 r14 = sub3(e2, s1);

    // Faces via 3 crosses:
    //   f0 = r13 x r14, c1 = r12 x r13, c2 = r12 x r14
    //   f1 = c2, f2 = c2 - c1 - f0, f3 = -c1
    //   sign = dot(cross(r34, r12), r13) = -dot(c2, r13)
    F3 f0 = cross3(r13, r14);
    F3 c1 = cross3(r12, r13);
    F3 c2 = cross3(r12, r14);
    F3 f2 = sub3(sub3(c2, c1), f0);

    float q0 = dot3(f0, f0);
    float q1 = dot3(c2, c2);
    float q2 = dot3(f2, f2);
    float q3 = dot3(c1, c1);

    float g = asin_term( dot3(f0, c2), q0, q1)
            + asin_term( dot3(c2, f2), q1, q2)
            + asin_term(-dot3(f2, c1), q2, q3)
            + asin_term(-dot3(c1, f0), q3, q0);

    float sg = -dot3(c2, r13);
    sT[t] = (sg > 0.0f) ? g : -g;
    if (t == 0) sT[256] = 0.0f;

    // bbox overlap on wave 1 (lanes 64..127), fed from LDS.
    if ((t & 192) == 64) {
        int half = (t >> 5) & 1;             // 0: motion1, 1: motion2
        int jj = t & 31;
        if (jj > NJOINTS - 1) jj = NJOINTS - 1;  // pad lanes replicate joint 21
        const float* s = half ? sB : sA;
        float x = s[jj * 3 + 0];
        float z = s[jj * 3 + 2];
        float xn = x, xx = x, zn = z, zx = z;
#pragma unroll
        for (int k = 1; k < 32; k <<= 1) {
            xn = fminf(xn, __shfl_xor(xn, k, 32));
            xx = fmaxf(xx, __shfl_xor(xx, k, 32));
            zn = fminf(zn, __shfl_xor(zn, k, 32));
            zx = fmaxf(zx, __shfl_xor(zx, k, 32));
        }
        // swap halves: pull motion2's extents into lanes 64..95
        float oxn = __shfl_xor(xn, 32, 64);
        float oxx = __shfl_xor(xx, 32, 64);
        float ozn = __shfl_xor(zn, 32, 64);
        float ozx = __shfl_xor(zx, 32, 64);
        if (t == 64) {
            bool ovx = !((xx < oxn) || (oxx < xn));
            bool ovz = !((zx < ozn) || (ozx < zn));
            ov[f] = (ovx && ovz) ? 1 : 0;
        }
    }
    __syncthreads();

    if (t < NPAIRS) {
        int pa = (t * 205) >> 10;   // t/5 for t<25
        int pb = t - pa * 5;        // t%5
        int ia0 = c_pstart[pa], na = c_plen[pa];
        int ib0 = c_pstart[pb], nb = c_plen[pb];
        float s = 0.0f;
#pragma unroll
        for (int ka = 0; ka < 4; ka++) {
#pragma unroll
            for (int kb = 0; kb < 4; kb++) {
                int idx = (ka < na && kb < nb) ? ((ia0 + ka) * 16 + (ib0 + kb)) : 256;
                s += sT[idx];
            }
        }
        gli[(size_t)f * GSTRIDE + t] = s * 0.07957747154594767f;  // 1/(4*pi)
    }
}

// out[f] = max_j | gli[f+1][j]*mask[f+1] - gli[f][j]*mask[f] |
// mask[i] = ov[i-1] | ov[i] | ov[i+1]  (out-of-range -> false)
__global__ void k_out(const float* __restrict__ gli, const int* __restrict__ ov,
                      float* __restrict__ out) {
    int f = blockIdx.x * blockDim.x + threadIdx.x;
    if (f >= NFRAMES - 1) return;

    int m0 = ov[f];
    if (f > 0) m0 |= ov[f - 1];
    m0 |= ov[f + 1];

    int m1 = ov[f + 1] | ov[f];
    if (f + 2 <= NFRAMES - 1) m1 |= ov[f + 2];

    float ma = m0 ? 1.0f : 0.0f;
    float mb = m1 ? 1.0f : 0.0f;

    const float4* g0v = (const float4*)(gli + (size_t)f * GSTRIDE);        // 128B-aligned
    const float4* g1v = (const float4*)(gli + (size_t)(f + 1) * GSTRIDE);
    float v = 0.0f;
#pragma unroll
    for (int q = 0; q < 6; q++) {
        float4 u0 = g0v[q];
        float4 u1 = g1v[q];
        v = fmaxf(v, fabsf(u1.x * mb - u0.x * ma));
        v = fmaxf(v, fabsf(u1.y * mb - u0.y * ma));
        v = fmaxf(v, fabsf(u1.z * mb - u0.z * ma));
        v = fmaxf(v, fabsf(u1.w * mb - u0.w * ma));
    }
    {
        float u0 = ((const float*)g0v)[24];
        float u1 = ((const float*)g1v)[24];
        v = fmaxf(v, fabsf(u1 * mb - u0 * ma));
    }
    out[f] = v;
}

extern "C" void kernel_launch(void* const* d_in, const int* in_sizes, int n_in,
                              void* d_out, int out_size, void* d_ws, size_t ws_size,
                              hipStream_t stream) {
    const float* m1 = (const float*)d_in[0];
    const float* m2 = (const float*)d_in[1];
    float* out = (float*)d_out;

    float* gli = (float*)d_ws;                          // NFRAMES*GSTRIDE floats = 2 MB
    int* ov = (int*)(gli + (size_t)NFRAMES * GSTRIDE);  // NFRAMES ints

    k_gli<<<NFRAMES, 256, 0, stream>>>(m1, m2, gli, ov);

    {
        int threads = 256;
        int blocks = (NFRAMES - 1 + threads - 1) / threads;
        k_out<<<blocks, threads, 0, stream>>>(gli, ov, out);
    }
}

// Round 6
// 83.863 us; speedup vs baseline: 1.0468x; 1.0092x over previous
//
#include <hip/hip_runtime.h>
#include <math.h>

#define NFRAMES 16384
#define NJOINTS 22
#define NPATHS  5
#define NPAIRS  (NPATHS * NPATHS)
#define NSEG    16      // segments per motion: 3+3+4+3+3
#define GSTRIDE 32      // padded gli row stride (floats) -> 128B-aligned rows
#define FSTR    (NJOINTS * 3)   // 66 floats per frame per motion

// Per-segment float offsets (joint*3) into a frame: {start, end}.
// path0 (2,5)(5,8)(8,11); path1 (1,4)(4,7)(7,10);
// path2 (3,6)(6,9)(9,12)(12,15); path3 (14,17)(17,19)(19,21);
// path4 (13,16)(16,18)(18,20).
__constant__ int2 c_seg[NSEG] = {
    {6,15},{15,24},{24,33},
    {3,12},{12,21},{21,30},
    {9,18},{18,27},{27,36},{36,45},
    {42,51},{51,57},{57,63},
    {39,48},{48,54},{54,60}
};
__constant__ int c_pstart[NPATHS] = {0, 3, 6, 10, 13};
__constant__ int c_plen[NPATHS]   = {3, 3, 4, 3, 3};

struct F3 { float x, y, z; };
__device__ __forceinline__ F3 mk3(float x, float y, float z) { F3 r; r.x=x; r.y=y; r.z=z; return r; }
__device__ __forceinline__ F3 sub3(F3 a, F3 b) { return mk3(a.x-b.x, a.y-b.y, a.z-b.z); }
__device__ __forceinline__ float dot3(F3 a, F3 b) { return a.x*b.x + a.y*b.y + a.z*b.z; }
__device__ __forceinline__ F3 cross3(F3 a, F3 b) {
    return mk3(a.y*b.z - a.z*b.y,
               a.z*b.x - a.x*b.z,
               a.x*b.y - a.y*b.x);
}

// asin via A&S 4.4.45 (degree-3): acos(a)=sqrt(1-a)*poly(a), |eps|<=6.7e-5 rad.
__device__ __forceinline__ float fast_asin(float x) {
    float a = fabsf(x);
    float p = fmaf(a, -0.0187293f,  0.0742610f);
    p = fmaf(a, p, -0.2121144f);
    p = fmaf(a, p,  1.5707288f);
    float r = 1.5707963268f - __builtin_amdgcn_sqrtf(1.0f - a) * p;
    return copysignf(r, x);
}

// asin(clamp(d / sqrt(ma*mb))) with jnp safe-normalize semantics
// (zero-norm face -> normalized vec = 0 -> dot 0 -> asin 0)
__device__ __forceinline__ float asin_term(float d, float ma, float mb) {
    float rs = __builtin_amdgcn_rsqf(ma * mb);
    float x = fminf(1.0f, fmaxf(-1.0f, d * rs));
    float r = fast_asin(x);
    return (ma > 0.0f && mb > 0.0f) ? r : 0.0f;
}

// Signed GLI term for one segment pair, frame data in LDS:
// s[0..66) = motion1 frame, s[66..132) = motion2 frame.
__device__ __forceinline__ float gli_term(const float* __restrict__ s,
                                          int2 o1, int2 o2) {
    F3 s1 = mk3(s[o1.x], s[o1.x+1], s[o1.x+2]);
    F3 e1 = mk3(s[o1.y], s[o1.y+1], s[o1.y+2]);
    F3 s2 = mk3(s[FSTR+o2.x], s[FSTR+o2.x+1], s[FSTR+o2.x+2]);
    F3 e2 = mk3(s[FSTR+o2.y], s[FSTR+o2.y+1], s[FSTR+o2.y+2]);

    F3 r12 = sub3(e1, s1);
    F3 r13 = sub3(s2, s1);
    F3 r14 = sub3(e2, s1);

    // Faces via 3 crosses:
    //   f0 = r13 x r14, c1 = r12 x r13, c2 = r12 x r14
    //   f1 = c2, f2 = c2 - c1 - f0, f3 = -c1
    //   sign = dot(cross(r34, r12), r13) = -dot(c2, r13)
    F3 f0 = cross3(r13, r14);
    F3 c1 = cross3(r12, r13);
    F3 c2 = cross3(r12, r14);
    F3 f2 = sub3(sub3(c2, c1), f0);

    float q0 = dot3(f0, f0);
    float q1 = dot3(c2, c2);
    float q2 = dot3(f2, f2);
    float q3 = dot3(c1, c1);

    float g = asin_term( dot3(f0, c2), q0, q1)
            + asin_term( dot3(c2, f2), q1, q2)
            + asin_term(-dot3(f2, c1), q2, q3)
            + asin_term(-dot3(c1, f0), q3, q0);

    float sg = -dot3(c2, r13);
    return (sg > 0.0f) ? g : -g;
}

// One block (256 threads) per TWO frames (f0 = 2*blockIdx.x, f1 = f0+1).
//  - coalesced staging of both frames' 2x66 floats into LDS, one barrier
//  - thread t computes the GLI term for segment pair (t>>4, t&15) for BOTH
//    frames (independent chains -> 2x ILP on the rsq/sqrt critical path)
//  - wave1 computes frame0's bbox-overlap flag, wave2 frame1's (width-32
//    shuffle butterflies + width-64 half-swap; no extra barrier)
//  - after the second barrier, lanes 0..24 bin-reduce frame0 and lanes
//    32..56 frame1 via fully unrolled padded LDS gathers
__global__ __launch_bounds__(256) void k_gli(const float* __restrict__ m1,
                                             const float* __restrict__ m2,
                                             float* __restrict__ gli,
                                             int* __restrict__ ov) {
    __shared__ float sF[2 * 2 * FSTR];   // [frame][motion] = 264 floats
    __shared__ float sT0[257];           // [256] = 0.0 pad slot
    __shared__ float sT1[257];

    int f0 = blockIdx.x * 2;
    int t = threadIdx.x;
    const float* a0 = m1 + (size_t)f0 * FSTR;
    const float* b0 = m2 + (size_t)f0 * FSTR;
    const float* a1 = a0 + FSTR;
    const float* b1 = b0 + FSTR;

    // Stage: floats [0,66) = a0, [66,132) = b0, [132,198) = a1, [198,264) = b1
    if (t < 2 * FSTR) {
        sF[t] = (t < FSTR) ? a0[t] : b0[t - FSTR];
    } else {
        int u = t - 2 * FSTR;            // u in [0, 124)
        sF[2 * FSTR + u] = (u < FSTR) ? a1[u] : b1[u - FSTR];
    }
    if (t < 8) sF[2 * FSTR + 124 + t] = b1[58 + t];   // tail of frame1's B
    if (t == 0) { sT0[256] = 0.0f; sT1[256] = 0.0f; }
    __syncthreads();

    int i = t >> 4;
    int j = t & 15;
    int2 o1 = c_seg[i];
    int2 o2 = c_seg[j];
    float g0 = gli_term(sF, o1, o2);
    float g1 = gli_term(sF + 2 * FSTR, o1, o2);
    sT0[t] = g0;
    sT1[t] = g1;

    // bbox overlap: wave1 -> frame0, wave2 -> frame1
    int w = t >> 6;
    if (w == 1 || w == 2) {
        const float* s = sF + (w - 1) * (2 * FSTR);
        int half = (t >> 5) & 1;             // 0: motion1, 1: motion2
        int jj = t & 31;
        if (jj > NJOINTS - 1) jj = NJOINTS - 1;  // pad lanes replicate joint 21
        const float* p = s + half * FSTR;
        float x = p[jj * 3 + 0];
        float z = p[jj * 3 + 2];
        float xn = x, xx = x, zn = z, zx = z;
#pragma unroll
        for (int k = 1; k < 32; k <<= 1) {
            xn = fminf(xn, __shfl_xor(xn, k, 32));
            xx = fmaxf(xx, __shfl_xor(xx, k, 32));
            zn = fminf(zn, __shfl_xor(zn, k, 32));
            zx = fmaxf(zx, __shfl_xor(zx, k, 32));
        }
        // swap halves within the wave: pull the other motion's extents
        float oxn = __shfl_xor(xn, 32, 64);
        float oxx = __shfl_xor(xx, 32, 64);
        float ozn = __shfl_xor(zn, 32, 64);
        float ozx = __shfl_xor(zx, 32, 64);
        if ((t & 63) == 0) {
            bool ovx = !((xx < oxn) || (oxx < xn));
            bool ovz = !((zx < ozn) || (ozx < zn));
            ov[f0 + (w - 1)] = (ovx && ovz) ? 1 : 0;
        }
    }
    __syncthreads();

    // Bin-reduce: lanes 0..24 frame0, lanes 32..56 frame1.
    int tt = -1;
    const float* sT = sT0;
    int fo = f0;
    if (t < NPAIRS) { tt = t; }
    else if (t >= 32 && t < 32 + NPAIRS) { tt = t - 32; sT = sT1; fo = f0 + 1; }
    if (tt >= 0) {
        int pa = (tt * 205) >> 10;   // tt/5 for tt<25
        int pb = tt - pa * 5;        // tt%5
        int ia0 = c_pstart[pa], na = c_plen[pa];
        int ib0 = c_pstart[pb], nb = c_plen[pb];
        float s = 0.0f;
#pragma unroll
        for (int ka = 0; ka < 4; ka++) {
#pragma unroll
            for (int kb = 0; kb < 4; kb++) {
                int idx = (ka < na && kb < nb) ? ((ia0 + ka) * 16 + (ib0 + kb)) : 256;
                s += sT[idx];
            }
        }
        gli[(size_t)fo * GSTRIDE + tt] = s * 0.07957747154594767f;  // 1/(4*pi)
    }
}

// out[f] = max_j | gli[f+1][j]*mask[f+1] - gli[f][j]*mask[f] |
// mask[i] = ov[i-1] | ov[i] | ov[i+1]  (out-of-range -> false)
__global__ void k_out(const float* __restrict__ gli, const int* __restrict__ ov,
                      float* __restrict__ out) {
    int f = blockIdx.x * blockDim.x + threadIdx.x;
    if (f >= NFRAMES - 1) return;

    int m0 = ov[f];
    if (f > 0) m0 |= ov[f - 1];
    m0 |= ov[f + 1];

    int m1 = ov[f + 1] | ov[f];
    if (f + 2 <= NFRAMES - 1) m1 |= ov[f + 2];

    float ma = m0 ? 1.0f : 0.0f;
    float mb = m1 ? 1.0f : 0.0f;

    const float4* g0v = (const float4*)(gli + (size_t)f * GSTRIDE);        // 128B-aligned
    const float4* g1v = (const float4*)(gli + (size_t)(f + 1) * GSTRIDE);
    float v = 0.0f;
#pragma unroll
    for (int q = 0; q < 6; q++) {
        float4 u0 = g0v[q];
        float4 u1 = g1v[q];
        v = fmaxf(v, fabsf(u1.x * mb - u0.x * ma));
        v = fmaxf(v, fabsf(u1.y * mb - u0.y * ma));
        v = fmaxf(v, fabsf(u1.z * mb - u0.z * ma));
        v = fmaxf(v, fabsf(u1.w * mb - u0.w * ma));
    }
    {
        float u0 = ((const float*)g0v)[24];
        float u1 = ((const float*)g1v)[24];
        v = fmaxf(v, fabsf(u1 * mb - u0 * ma));
    }
    out[f] = v;
}

extern "C" void kernel_launch(void* const* d_in, const int* in_sizes, int n_in,
                              void* d_out, int out_size, void* d_ws, size_t ws_size,
                              hipStream_t stream) {
    const float* m1 = (const float*)d_in[0];
    const float* m2 = (const float*)d_in[1];
    float* out = (float*)d_out;

    float* gli = (float*)d_ws;                          // NFRAMES*GSTRIDE floats = 2 MB
    int* ov = (int*)(gli + (size_t)NFRAMES * GSTRIDE);  // NFRAMES ints

    k_gli<<<NFRAMES / 2, 256, 0, stream>>>(m1, m2, gli, ov);

    {
        int threads = 256;
        int blocks = (NFRAMES - 1 + threads - 1) / threads;
        k_out<<<blocks, threads, 0, stream>>>(gli, ov, out);
    }
}

// Round 7
// 80.690 us; speedup vs baseline: 1.0879x; 1.0393x over previous
//
#include <hip/hip_runtime.h>
#include <math.h>

#define NFRAMES 16384
#define NJOINTS 22
#define NPATHS  5
#define NPAIRS  (NPATHS * NPATHS)
#define NSEG    16      // segments per motion: 3+3+4+3+3
#define GSTRIDE 32      // padded gli row stride (floats) -> 128B-aligned rows
#define FSTR    (NJOINTS * 3)   // 66 floats per frame per motion

typedef float v2f __attribute__((ext_vector_type(2)));

// Per-segment float offsets (joint*3) into a frame: {start, end}.
// path0 (2,5)(5,8)(8,11); path1 (1,4)(4,7)(7,10);
// path2 (3,6)(6,9)(9,12)(12,15); path3 (14,17)(17,19)(19,21);
// path4 (13,16)(16,18)(18,20).
__constant__ int2 c_seg[NSEG] = {
    {6,15},{15,24},{24,33},
    {3,12},{12,21},{21,30},
    {9,18},{18,27},{27,36},{36,45},
    {42,51},{51,57},{57,63},
    {39,48},{48,54},{54,60}
};
__constant__ int c_pstart[NPATHS] = {0, 3, 6, 10, 13};
__constant__ int c_plen[NPATHS]   = {3, 3, 4, 3, 3};

// Packed 2-frame 3-vector: .x/.y/.z are v2f holding {frame0, frame1}.
struct V3 { v2f x, y, z; };
__device__ __forceinline__ V3 vsub(V3 a, V3 b) { V3 r; r.x=a.x-b.x; r.y=a.y-b.y; r.z=a.z-b.z; return r; }
__device__ __forceinline__ v2f vdot(V3 a, V3 b) { return a.x*b.x + a.y*b.y + a.z*b.z; }
__device__ __forceinline__ V3 vcross(V3 a, V3 b) {
    V3 r;
    r.x = a.y*b.z - a.z*b.y;
    r.y = a.z*b.x - a.x*b.z;
    r.z = a.x*b.y - a.y*b.x;
    return r;
}

// asin via A&S 4.4.45 (degree-3): acos(a)=sqrt(1-a)*poly(a), |eps|<=6.7e-5 rad.
// Packed over two frames; sqrt + final sign-restore are per-component.
__device__ __forceinline__ v2f vfast_asin(v2f x) {
    v2f a = __builtin_elementwise_max(x, -x);   // |x|
    v2f p = a * -0.0187293f + 0.0742610f;
    p = a * p + -0.2121144f;
    p = a * p + 1.5707288f;
    v2f s;
    s.x = __builtin_amdgcn_sqrtf(1.0f - a.x);
    s.y = __builtin_amdgcn_sqrtf(1.0f - a.y);
    v2f r = 1.5707963268f - s * p;
    r.x = (x.x < 0.0f) ? -r.x : r.x;
    r.y = (x.y < 0.0f) ? -r.y : r.y;
    return r;
}

// asin(clamp(d / sqrt(ma*mb))) with jnp safe-normalize semantics
// (zero-norm face -> normalized vec = 0 -> dot 0 -> asin 0)
__device__ __forceinline__ v2f vasin_term(v2f d, v2f ma, v2f mb) {
    v2f m = ma * mb;
    v2f rs;
    rs.x = __builtin_amdgcn_rsqf(m.x);
    rs.y = __builtin_amdgcn_rsqf(m.y);
    v2f one = 1.0f, mone = -1.0f;
    v2f x = __builtin_elementwise_min(one, __builtin_elementwise_max(mone, d * rs));
    v2f r = vfast_asin(x);
    r.x = (ma.x > 0.0f && mb.x > 0.0f) ? r.x : 0.0f;
    r.y = (ma.y > 0.0f && mb.y > 0.0f) ? r.y : 0.0f;
    return r;
}

// One block (256 threads) per TWO frames (f0 = 2*blockIdx.x, f1 = f0+1).
//  - LDS holds both frames interleaved [coord][frame] so one ds_read_b64
//    fetches a coord for both frames (v2f)
//  - thread t computes the GLI term for segment pair (t>>4, t&15) for both
//    frames simultaneously via packed fp32 (v_pk_* on gfx950)
//  - wave1 computes frame0's bbox-overlap flag, wave2 frame1's
//  - after the barrier, lanes 0..24 bin-reduce frame0, lanes 32..56 frame1
__global__ __launch_bounds__(256) void k_gli(const float* __restrict__ m1,
                                             const float* __restrict__ m2,
                                             float* __restrict__ gli,
                                             int* __restrict__ ov) {
    __shared__ v2f sA[FSTR];    // sA[k] = {m1 frame0 coord k, m1 frame1 coord k}
    __shared__ v2f sB[FSTR];
    __shared__ float sT0[257];  // [256] = 0.0 pad slot
    __shared__ float sT1[257];

    int f0 = blockIdx.x * 2;
    int t = threadIdx.x;
    const float* a0 = m1 + (size_t)f0 * FSTR;   // frame0 motion1; frame1 at +FSTR
    const float* b0 = m2 + (size_t)f0 * FSTR;

    float* sAf = (float*)sA;
    float* sBf = (float*)sB;
    // Coalesced global reads, stride-2 LDS writes (2-way aliasing is free).
    if (t < FSTR)               sAf[2 * t] = a0[t];
    else if (t < 2 * FSTR)      sBf[2 * (t - FSTR)] = b0[t - FSTR];
    else if (t < 3 * FSTR)      sAf[2 * (t - 2 * FSTR) + 1] = a0[FSTR + (t - 2 * FSTR)];
    else                        sBf[2 * (t - 3 * FSTR) + 1] = b0[FSTR + (t - 3 * FSTR)];
    if (t < 8)                  sBf[2 * (58 + t) + 1] = b0[FSTR + 58 + t];  // b1 tail
    if (t == 0) { sT0[256] = 0.0f; sT1[256] = 0.0f; }
    __syncthreads();

    int i = t >> 4;
    int j = t & 15;
    int2 o1 = c_seg[i];
    int2 o2 = c_seg[j];
    V3 s1; s1.x = sA[o1.x]; s1.y = sA[o1.x+1]; s1.z = sA[o1.x+2];
    V3 e1; e1.x = sA[o1.y]; e1.y = sA[o1.y+1]; e1.z = sA[o1.y+2];
    V3 s2; s2.x = sB[o2.x]; s2.y = sB[o2.x+1]; s2.z = sB[o2.x+2];
    V3 e2; e2.x = sB[o2.y]; e2.y = sB[o2.y+1]; e2.z = sB[o2.y+2];

    V3 r12 = vsub(e1, s1);
    V3 r13 = vsub(s2, s1);
    V3 r14 = vsub(e2, s1);

    // Faces via 3 crosses:
    //   f0v = r13 x r14, c1 = r12 x r13, c2 = r12 x r14
    //   f1 = c2, f2 = c2 - c1 - f0v, f3 = -c1
    //   sign = dot(cross(r34, r12), r13) = -dot(c2, r13)
    V3 f0v = vcross(r13, r14);
    V3 c1  = vcross(r12, r13);
    V3 c2  = vcross(r12, r14);
    V3 f2  = vsub(vsub(c2, c1), f0v);

    v2f q0 = vdot(f0v, f0v);
    v2f q1 = vdot(c2, c2);
    v2f q2 = vdot(f2, f2);
    v2f q3 = vdot(c1, c1);

    v2f g = vasin_term( vdot(f0v, c2), q0, q1)
          + vasin_term( vdot(c2, f2),  q1, q2)
          + vasin_term(-vdot(f2, c1),  q2, q3)
          + vasin_term(-vdot(c1, f0v), q3, q0);

    v2f sg = -vdot(c2, r13);
    sT0[t] = (sg.x > 0.0f) ? g.x : -g.x;
    sT1[t] = (sg.y > 0.0f) ? g.y : -g.y;

    // bbox overlap: wave1 -> frame0, wave2 -> frame1 (fed from LDS).
    int w = t >> 6;
    if (w == 1 || w == 2) {
        int fr = w - 1;
        int half = (t >> 5) & 1;             // 0: motion1, 1: motion2
        int jj = t & 31;
        if (jj > NJOINTS - 1) jj = NJOINTS - 1;  // pad lanes replicate joint 21
        const float* p = (half ? sBf : sAf);
        float x = p[2 * (jj * 3 + 0) + fr];
        float z = p[2 * (jj * 3 + 2) + fr];
        float xn = x, xx = x, zn = z, zx = z;
#pragma unroll
        for (int k = 1; k < 32; k <<= 1) {
            xn = fminf(xn, __shfl_xor(xn, k, 32));
            xx = fmaxf(xx, __shfl_xor(xx, k, 32));
            zn = fminf(zn, __shfl_xor(zn, k, 32));
            zx = fmaxf(zx, __shfl_xor(zx, k, 32));
        }
        // swap halves within the wave: pull the other motion's extents
        float oxn = __shfl_xor(xn, 32, 64);
        float oxx = __shfl_xor(xx, 32, 64);
        float ozn = __shfl_xor(zn, 32, 64);
        float ozx = __shfl_xor(zx, 32, 64);
        if ((t & 63) == 0) {
            bool ovx = !((xx < oxn) || (oxx < xn));
            bool ovz = !((zx < ozn) || (ozx < zn));
            ov[f0 + fr] = (ovx && ovz) ? 1 : 0;
        }
    }
    __syncthreads();

    // Bin-reduce: lanes 0..24 frame0, lanes 32..56 frame1.
    int tt = -1;
    const float* sT = sT0;
    int fo = f0;
    if (t < NPAIRS) { tt = t; }
    else if (t >= 32 && t < 32 + NPAIRS) { tt = t - 32; sT = sT1; fo = f0 + 1; }
    if (tt >= 0) {
        int pa = (tt * 205) >> 10;   // tt/5 for tt<25
        int pb = tt - pa * 5;        // tt%5
        int ia0 = c_pstart[pa], na = c_plen[pa];
        int ib0 = c_pstart[pb], nb = c_plen[pb];
        float s = 0.0f;
#pragma unroll
        for (int ka = 0; ka < 4; ka++) {
#pragma unroll
            for (int kb = 0; kb < 4; kb++) {
                int idx = (ka < na && kb < nb) ? ((ia0 + ka) * 16 + (ib0 + kb)) : 256;
                s += sT[idx];
            }
        }
        gli[(size_t)fo * GSTRIDE + tt] = s * 0.07957747154594767f;  // 1/(4*pi)
    }
}

// out[f] = max_j | gli[f+1][j]*mask[f+1] - gli[f][j]*mask[f] |
// mask[i] = ov[i-1] | ov[i] | ov[i+1]  (out-of-range -> false)
__global__ void k_out(const float* __restrict__ gli, const int* __restrict__ ov,
                      float* __restrict__ out) {
    int f = blockIdx.x * blockDim.x + threadIdx.x;
    if (f >= NFRAMES - 1) return;

    int m0 = ov[f];
    if (f > 0) m0 |= ov[f - 1];
    m0 |= ov[f + 1];

    int m1 = ov[f + 1] | ov[f];
    if (f + 2 <= NFRAMES - 1) m1 |= ov[f + 2];

    float ma = m0 ? 1.0f : 0.0f;
    float mb = m1 ? 1.0f : 0.0f;

    const float4* g0v = (const float4*)(gli + (size_t)f * GSTRIDE);        // 128B-aligned
    const float4* g1v = (const float4*)(gli + (size_t)(f + 1) * GSTRIDE);
    float v = 0.0f;
#pragma unroll
    for (int q = 0; q < 6; q++) {
        float4 u0 = g0v[q];
        float4 u1 = g1v[q];
        v = fmaxf(v, fabsf(u1.x * mb - u0.x * ma));
        v = fmaxf(v, fabsf(u1.y * mb - u0.y * ma));
        v = fmaxf(v, fabsf(u1.z * mb - u0.z * ma));
        v = fmaxf(v, fabsf(u1.w * mb - u0.w * ma));
    }
    {
        float u0 = ((const float*)g0v)[24];
        float u1 = ((const float*)g1v)[24];
        v = fmaxf(v, fabsf(u1 * mb - u0 * ma));
    }
    out[f] = v;
}

extern "C" void kernel_launch(void* const* d_in, const int* in_sizes, int n_in,
                              void* d_out, int out_size, void* d_ws, size_t ws_size,
                              hipStream_t stream) {
    const float* m1 = (const float*)d_in[0];
    const float* m2 = (const float*)d_in[1];
    float* out = (float*)d_out;

    float* gli = (float*)d_ws;                          // NFRAMES*GSTRIDE floats = 2 MB
    int* ov = (int*)(gli + (size_t)NFRAMES * GSTRIDE);  // NFRAMES ints

    k_gli<<<NFRAMES / 2, 256, 0, stream>>>(m1, m2, gli, ov);

    {
        int threads = 256;
        int blocks = (NFRAMES - 1 + threads - 1) / threads;
        k_out<<<blocks, threads, 0, stream>>>(gli, ov, out);
    }
}